// Round 1
// baseline (245.580 us; speedup 1.0000x reference)
//
#include <hip/hip_runtime.h>

#define HNUM 240
#define WNUM 1216
#define BNUM 4
#define HWN (HNUM * WNUM)
#define NPIX (BNUM * HWN)

// ---------------------------------------------------------------------------
// init: ff0 = pred_init * conf
// ---------------------------------------------------------------------------
__global__ __launch_bounds__(256) void nlspn_init_kernel(
    const float* __restrict__ pred,
    const float* __restrict__ conf,
    float* __restrict__ ff)
{
    int p = blockIdx.x * blockDim.x + threadIdx.x;
    if (p < NPIX) ff[p] = pred[p] * conf[p];
}

// ---------------------------------------------------------------------------
// one propagation step:
//   aff   = tanh(aff_raw) / (s+1e-8); normalize by max(sum|aff|+1e-4, 1)
//   aff_ref = 1 - sum(aff)
//   out[p] = sum_k aff9_k * bilinear(ff, (y,x)+(dy,dx)+off_k)   (zero pad)
//   out[p] = dep>0 ? dep : out[p]
//   write LAST ? out : out*conf
// ---------------------------------------------------------------------------
template <bool LAST>
__global__ __launch_bounds__(256) void nlspn_prop_kernel(
    const float* __restrict__ aff_raw,   // [B,8,H,W]
    const float* __restrict__ offset,    // [B,16,H,W]  (y,x interleaved per nb)
    const float* __restrict__ conf,      // [B,1,H,W]
    const float* __restrict__ dep,       // [B,1,H,W]
    const float* __restrict__ scale,     // [1]
    const float* __restrict__ ff_in,     // [B,H,W]  = feat*conf of prev step
    float* __restrict__ out)             // [B,H,W]
{
    int p = blockIdx.x * blockDim.x + threadIdx.x;
    if (p >= NPIX) return;
    int b  = p / HWN;
    int hw = p - b * HWN;
    int h  = hw / WNUM;
    int w  = hw - h * WNUM;

    float s    = scale[0];
    float invs = 1.0f / (s + 1e-8f);

    // --- affinity normalization (TGASS) ---
    float a[8];
    const float* ar = aff_raw + (size_t)b * 8 * HWN + hw;
#pragma unroll
    for (int k = 0; k < 8; ++k) a[k] = ar[(size_t)k * HWN];

    float asum = 0.0f;
#pragma unroll
    for (int k = 0; k < 8; ++k) {
        a[k] = tanhf(a[k]) * invs;
        asum += fabsf(a[k]);
    }
    asum += 1e-4f;
    float rden = 1.0f / fmaxf(asum, 1.0f);
    float suma = 0.0f;
#pragma unroll
    for (int k = 0; k < 8; ++k) {
        a[k] *= rden;
        suma += a[k];
    }
    float aref = 1.0f - suma;

    const float* ffb = ff_in + (size_t)b * HWN;
    float acc = aref * ffb[hw];   // center tap: exact sample at (h,w)

    // --- 8 deformable neighbor taps ---
    const float* off = offset + (size_t)b * 16 * HWN + hw;
#pragma unroll
    for (int k = 0; k < 8; ++k) {
        int   k9   = (k < 4) ? k : k + 1;
        int   dy   = k9 / 3 - 1;
        int   dx   = k9 - (k9 / 3) * 3 - 1;
        float offy = off[(size_t)(2 * k)     * HWN];
        float offx = off[(size_t)(2 * k + 1) * HWN];

        float ysf = (float)(h + dy) + offy;
        float xsf = (float)(w + dx) + offx;
        float y0f = floorf(ysf);
        float x0f = floorf(xsf);
        float wy  = ysf - y0f;
        float wx  = xsf - x0f;
        int   y0  = (int)y0f;
        int   x0  = (int)x0f;

        bool yv0 = (y0 >= 0)     & (y0 < HNUM);
        bool yv1 = (y0 >= -1)    & (y0 + 1 < HNUM);
        bool xv0 = (x0 >= 0)     & (x0 < WNUM);
        bool xv1 = (x0 >= -1)    & (x0 + 1 < WNUM);

        int row0 = y0 * WNUM;
        float g00 = 0.f, g01 = 0.f, g10 = 0.f, g11 = 0.f;
        if (yv0 & xv0) g00 = ffb[row0 + x0];
        if (yv0 & xv1) g01 = ffb[row0 + x0 + 1];
        if (yv1 & xv0) g10 = ffb[row0 + WNUM + x0];
        if (yv1 & xv1) g11 = ffb[row0 + WNUM + x0 + 1];

        float sampled = (1.f - wy) * ((1.f - wx) * g00 + wx * g01)
                      +        wy  * ((1.f - wx) * g10 + wx * g11);
        acc += a[k] * sampled;
    }

    // --- sparse-depth fixing ---
    float d    = dep[p];
    float feat = (d > 0.0f) ? d : acc;

    if (LAST) out[p] = feat;
    else      out[p] = feat * conf[p];
}

// ---------------------------------------------------------------------------
extern "C" void kernel_launch(void* const* d_in, const int* in_sizes, int n_in,
                              void* d_out, int out_size, void* d_ws, size_t ws_size,
                              hipStream_t stream)
{
    const float* aff_raw = (const float*)d_in[0];
    const float* offset  = (const float*)d_in[1];
    const float* conf    = (const float*)d_in[2];
    const float* pred    = (const float*)d_in[3];
    const float* dep     = (const float*)d_in[4];
    const float* scale   = (const float*)d_in[5];
    float* out = (float*)d_out;
    float* ws  = (float*)d_ws;   // one N-float plane used as ping-pong partner

    const int threads = 256;
    const int blocks  = (NPIX + threads - 1) / threads;

    // ff ping-pong: A = d_out, B = d_ws. Final step writes feat into d_out.
    nlspn_init_kernel<<<blocks, threads, 0, stream>>>(pred, conf, out);        // ff0 -> A
    nlspn_prop_kernel<false><<<blocks, threads, 0, stream>>>(aff_raw, offset, conf, dep, scale, out, ws);  // A->B (ff1)
    nlspn_prop_kernel<false><<<blocks, threads, 0, stream>>>(aff_raw, offset, conf, dep, scale, ws, out);  // B->A (ff2)
    nlspn_prop_kernel<false><<<blocks, threads, 0, stream>>>(aff_raw, offset, conf, dep, scale, out, ws);  // A->B (ff3)
    nlspn_prop_kernel<false><<<blocks, threads, 0, stream>>>(aff_raw, offset, conf, dep, scale, ws, out);  // B->A (ff4)
    nlspn_prop_kernel<false><<<blocks, threads, 0, stream>>>(aff_raw, offset, conf, dep, scale, out, ws);  // A->B (ff5)
    nlspn_prop_kernel<true ><<<blocks, threads, 0, stream>>>(aff_raw, offset, conf, dep, scale, ws, out);  // B-> d_out (feat)
}

// Round 2
// 152.566 us; speedup vs baseline: 1.6097x; 1.6097x over previous
//
#include <hip/hip_runtime.h>
#include <stdint.h>

#define HNUM 240
#define WNUM 1216
#define BNUM 4
#define HWN (HNUM * WNUM)
#define NPIX (BNUM * HWN)
#define WP (WNUM + 3)
#define HP (HNUM + 3)
#define PLANE (HP * WP)
#define NPLANE (BNUM * PLANE)

// ---------------------------------------------------------------------------
// fast tanh via hardware exp2:  tanh(|x|) = 1 - 2/(exp2(2*log2e*|x|)+1)
// ---------------------------------------------------------------------------
__device__ __forceinline__ float fast_tanh(float x) {
    float ax = fabsf(x);
    float e  = __builtin_amdgcn_exp2f(ax * 2.885390081777927f);  // 2*log2(e)
    float t  = 1.0f - 2.0f * __builtin_amdgcn_rcpf(e + 1.0f);
    return copysignf(t, x);
}

union HCV { uint32_t u; _Float16 h[2]; };

// ---------------------------------------------------------------------------
// init: padded planes. planeA interior = pred*conf; both planes' borders = 0.
// ---------------------------------------------------------------------------
__global__ __launch_bounds__(256) void nlspn_init_pad(
    const float* __restrict__ pred,
    const float* __restrict__ conf,
    float* __restrict__ planeA,
    float* __restrict__ planeB)
{
    int i = blockIdx.x * blockDim.x + threadIdx.x;
    if (i >= NPLANE) return;
    int b    = i / PLANE;
    int cell = i - b * PLANE;
    int ph   = cell / WP;
    int pw   = cell - ph * WP;
    int h = ph - 1, w = pw - 1;
    bool interior = (h >= 0) & (h < HNUM) & (w >= 0) & (w < WNUM);
    if (interior) {
        int p = b * HWN + h * WNUM + w;
        planeA[i] = pred[p] * conf[p];
    } else {
        planeA[i] = 0.f;
        planeB[i] = 0.f;
    }
}

// ---------------------------------------------------------------------------
// step 1 fused with meta build.
// meta per pixel: 8 taps packed u32 (int16 rel | u8 wy | u8 wx),
//                 8 affs fp16, aux = {half2(aref,conf), f32 dep}
// ---------------------------------------------------------------------------
__global__ __launch_bounds__(256) void nlspn_step1_build(
    const float* __restrict__ aff_raw,
    const float* __restrict__ offset,
    const float* __restrict__ conf,
    const float* __restrict__ dep,
    const float* __restrict__ scale,
    const float* __restrict__ ffpad_in,
    float* __restrict__ ffpad_out,
    uint4* __restrict__ tapsA,
    uint4* __restrict__ tapsB,
    uint4* __restrict__ affv,
    uint2* __restrict__ auxv)
{
    int p = blockIdx.x * blockDim.x + threadIdx.x;
    if (p >= NPIX) return;
    int b  = p / HWN;
    int hw = p - b * HWN;
    int h  = hw / WNUM;
    int w  = hw - h * WNUM;

    float s    = scale[0];
    float invs = 1.0f / (s + 1e-8f);

    const float* ar = aff_raw + (size_t)b * 8 * HWN + hw;
    float a[8];
    float asum = 0.f;
#pragma unroll
    for (int k = 0; k < 8; ++k) {
        float t = fast_tanh(ar[(size_t)k * HWN]) * invs;
        a[k] = t;
        asum += fabsf(t);
    }
    asum += 1e-4f;
    float rden = 1.0f / fmaxf(asum, 1.0f);
    float suma = 0.f;
#pragma unroll
    for (int k = 0; k < 8; ++k) { a[k] *= rden; suma += a[k]; }
    float aref = 1.0f - suma;

    const float* base_in = ffpad_in + (size_t)b * PLANE + (h + 1) * WP + (w + 1);
    float acc = aref * base_in[0];

    const float* off = offset + (size_t)b * 16 * HWN + hw;
    uint32_t tw[8];
#pragma unroll
    for (int k = 0; k < 8; ++k) {
        int   k9 = (k < 4) ? k : k + 1;
        int   dy = k9 / 3 - 1;
        int   dx = k9 - (k9 / 3) * 3 - 1;
        float offy = off[(size_t)(2 * k)     * HWN];
        float offx = off[(size_t)(2 * k + 1) * HWN];
        float ys  = (float)(h + dy) + offy;
        float xs  = (float)(w + dx) + offx;
        float y0f = floorf(ys), x0f = floorf(xs);
        int   y0  = (int)y0f,  x0  = (int)x0f;
        float wy  = ys - y0f,  wx  = xs - x0f;
        uint32_t qy = (uint32_t)(wy * 255.0f + 0.5f); if (qy > 255) qy = 255;
        uint32_t qx = (uint32_t)(wx * 255.0f + 0.5f); if (qx > 255) qx = 255;
        bool valid = (y0 >= -1) & (y0 <= HNUM) & (x0 >= -1) & (x0 <= WNUM);
        int rel = (y0 - h) * WP + (x0 - w);
        if (!valid || rel < -32768 || rel > 32767) { rel = 0; qy = 0; qx = 0; a[k] = 0.f; }
        tw[k] = (uint32_t)(uint16_t)(int16_t)rel | (qy << 16) | (qx << 24);

        float fwy = (float)qy * (1.0f / 255.0f);
        float fwx = (float)qx * (1.0f / 255.0f);
        const float* q = base_in + rel;
        float g00 = q[0], g01 = q[1], g10 = q[WP], g11 = q[WP + 1];
        float top = fmaf(fwx, g01 - g00, g00);
        float bot = fmaf(fwx, g11 - g10, g10);
        acc = fmaf(a[k], fmaf(fwy, bot - top, top), acc);
    }

    tapsA[p] = make_uint4(tw[0], tw[1], tw[2], tw[3]);
    tapsB[p] = make_uint4(tw[4], tw[5], tw[6], tw[7]);

    HCV cv;
    uint32_t aw[4];
#pragma unroll
    for (int k = 0; k < 4; ++k) {
        cv.h[0] = (_Float16)a[2 * k];
        cv.h[1] = (_Float16)a[2 * k + 1];
        aw[k] = cv.u;
    }
    affv[p] = make_uint4(aw[0], aw[1], aw[2], aw[3]);

    float d = dep[p];
    float c = conf[p];
    cv.h[0] = (_Float16)aref;
    cv.h[1] = (_Float16)c;
    auxv[p] = make_uint2(cv.u, __float_as_uint(d));

    float feat = (d > 0.f) ? d : acc;
    ffpad_out[(size_t)b * PLANE + (h + 1) * WP + (w + 1)] = feat * c;
}

// ---------------------------------------------------------------------------
// lean propagation step from packed meta, unconditional gathers
// ---------------------------------------------------------------------------
template <bool LAST>
__global__ __launch_bounds__(256) void nlspn_prop_meta(
    const uint4* __restrict__ tapsA,
    const uint4* __restrict__ tapsB,
    const uint4* __restrict__ affv,
    const uint2* __restrict__ auxv,
    const float* __restrict__ ffin,
    float* __restrict__ ffout,
    float* __restrict__ out)
{
    int p = blockIdx.x * blockDim.x + threadIdx.x;
    if (p >= NPIX) return;
    int b  = p / HWN;
    int hw = p - b * HWN;
    int h  = hw / WNUM;
    int w  = hw - h * WNUM;
    int bp = b * PLANE + (h + 1) * WP + (w + 1);

    uint4 t0 = tapsA[p];
    uint4 t1 = tapsB[p];
    uint4 av = affv[p];
    uint2 ax = auxv[p];

    HCV cv;
    float a[8];
    cv.u = av.x; a[0] = (float)cv.h[0]; a[1] = (float)cv.h[1];
    cv.u = av.y; a[2] = (float)cv.h[0]; a[3] = (float)cv.h[1];
    cv.u = av.z; a[4] = (float)cv.h[0]; a[5] = (float)cv.h[1];
    cv.u = av.w; a[6] = (float)cv.h[0]; a[7] = (float)cv.h[1];
    cv.u = ax.x;
    float aref = (float)cv.h[0];
    float c    = (float)cv.h[1];
    float d    = __uint_as_float(ax.y);

    const float* base = ffin + bp;
    float acc = aref * base[0];

    uint32_t tm[8] = {t0.x, t0.y, t0.z, t0.w, t1.x, t1.y, t1.z, t1.w};
#pragma unroll
    for (int k = 0; k < 8; ++k) {
        uint32_t m = tm[k];
        int   rel = (int)(int16_t)(m & 0xffffu);
        float wy  = (float)((m >> 16) & 0xffu) * (1.0f / 255.0f);
        float wx  = (float)(m >> 24)           * (1.0f / 255.0f);
        const float* q = base + rel;
        float g00 = q[0], g01 = q[1], g10 = q[WP], g11 = q[WP + 1];
        float top = fmaf(wx, g01 - g00, g00);
        float bot = fmaf(wx, g11 - g10, g10);
        acc = fmaf(a[k], fmaf(wy, bot - top, top), acc);
    }

    float feat = (d > 0.f) ? d : acc;
    if (LAST) out[p] = feat;
    else      ffout[bp] = feat * c;
}

// ---------------------------------------------------------------------------
// fallback (round-1 style) if workspace is too small
// ---------------------------------------------------------------------------
__global__ __launch_bounds__(256) void nlspn_init_kernel(
    const float* __restrict__ pred,
    const float* __restrict__ conf,
    float* __restrict__ ff)
{
    int p = blockIdx.x * blockDim.x + threadIdx.x;
    if (p < NPIX) ff[p] = pred[p] * conf[p];
}

template <bool LAST>
__global__ __launch_bounds__(256) void nlspn_prop_kernel(
    const float* __restrict__ aff_raw,
    const float* __restrict__ offset,
    const float* __restrict__ conf,
    const float* __restrict__ dep,
    const float* __restrict__ scale,
    const float* __restrict__ ff_in,
    float* __restrict__ out)
{
    int p = blockIdx.x * blockDim.x + threadIdx.x;
    if (p >= NPIX) return;
    int b  = p / HWN;
    int hw = p - b * HWN;
    int h  = hw / WNUM;
    int w  = hw - h * WNUM;

    float s    = scale[0];
    float invs = 1.0f / (s + 1e-8f);

    float a[8];
    const float* ar = aff_raw + (size_t)b * 8 * HWN + hw;
#pragma unroll
    for (int k = 0; k < 8; ++k) a[k] = ar[(size_t)k * HWN];

    float asum = 0.0f;
#pragma unroll
    for (int k = 0; k < 8; ++k) {
        a[k] = fast_tanh(a[k]) * invs;
        asum += fabsf(a[k]);
    }
    asum += 1e-4f;
    float rden = 1.0f / fmaxf(asum, 1.0f);
    float suma = 0.0f;
#pragma unroll
    for (int k = 0; k < 8; ++k) { a[k] *= rden; suma += a[k]; }
    float aref = 1.0f - suma;

    const float* ffb = ff_in + (size_t)b * HWN;
    float acc = aref * ffb[hw];

    const float* off = offset + (size_t)b * 16 * HWN + hw;
#pragma unroll
    for (int k = 0; k < 8; ++k) {
        int   k9 = (k < 4) ? k : k + 1;
        int   dy = k9 / 3 - 1;
        int   dx = k9 - (k9 / 3) * 3 - 1;
        float offy = off[(size_t)(2 * k)     * HWN];
        float offx = off[(size_t)(2 * k + 1) * HWN];
        float ysf = (float)(h + dy) + offy;
        float xsf = (float)(w + dx) + offx;
        float y0f = floorf(ysf);
        float x0f = floorf(xsf);
        float wy  = ysf - y0f;
        float wx  = xsf - x0f;
        int   y0  = (int)y0f;
        int   x0  = (int)x0f;
        bool yv0 = (y0 >= 0)  & (y0 < HNUM);
        bool yv1 = (y0 >= -1) & (y0 + 1 < HNUM);
        bool xv0 = (x0 >= 0)  & (x0 < WNUM);
        bool xv1 = (x0 >= -1) & (x0 + 1 < WNUM);
        int row0 = y0 * WNUM;
        float g00 = 0.f, g01 = 0.f, g10 = 0.f, g11 = 0.f;
        if (yv0 & xv0) g00 = ffb[row0 + x0];
        if (yv0 & xv1) g01 = ffb[row0 + x0 + 1];
        if (yv1 & xv0) g10 = ffb[row0 + WNUM + x0];
        if (yv1 & xv1) g11 = ffb[row0 + WNUM + x0 + 1];
        float sampled = (1.f - wy) * ((1.f - wx) * g00 + wx * g01)
                      +        wy  * ((1.f - wx) * g10 + wx * g11);
        acc += a[k] * sampled;
    }

    float dd   = dep[p];
    float feat = (dd > 0.0f) ? dd : acc;
    if (LAST) out[p] = feat;
    else      out[p] = feat * conf[p];
}

// ---------------------------------------------------------------------------
extern "C" void kernel_launch(void* const* d_in, const int* in_sizes, int n_in,
                              void* d_out, int out_size, void* d_ws, size_t ws_size,
                              hipStream_t stream)
{
    const float* aff_raw = (const float*)d_in[0];
    const float* offset  = (const float*)d_in[1];
    const float* conf    = (const float*)d_in[2];
    const float* pred    = (const float*)d_in[3];
    const float* dep     = (const float*)d_in[4];
    const float* scale   = (const float*)d_in[5];
    float* out = (float*)d_out;

    const int threads = 256;
    const int blocksP = (NPIX + threads - 1) / threads;
    const int blocksI = (NPLANE + threads - 1) / threads;

    const size_t need = (size_t)NPIX * 16 * 3 + (size_t)NPIX * 8
                      + (size_t)NPLANE * 4 * 2;

    if (ws_size >= need) {
        char* wb = (char*)d_ws;
        uint4* tapsA = (uint4*)wb;  wb += (size_t)NPIX * 16;
        uint4* tapsB = (uint4*)wb;  wb += (size_t)NPIX * 16;
        uint4* affv  = (uint4*)wb;  wb += (size_t)NPIX * 16;
        uint2* auxv  = (uint2*)wb;  wb += (size_t)NPIX * 8;
        float* plA   = (float*)wb;  wb += (size_t)NPLANE * 4;
        float* plB   = (float*)wb;

        nlspn_init_pad<<<blocksI, threads, 0, stream>>>(pred, conf, plA, plB);
        nlspn_step1_build<<<blocksP, threads, 0, stream>>>(
            aff_raw, offset, conf, dep, scale, plA, plB,
            tapsA, tapsB, affv, auxv);                                      // ff1 -> B
        nlspn_prop_meta<false><<<blocksP, threads, 0, stream>>>(
            tapsA, tapsB, affv, auxv, plB, plA, out);                       // ff2 -> A
        nlspn_prop_meta<false><<<blocksP, threads, 0, stream>>>(
            tapsA, tapsB, affv, auxv, plA, plB, out);                       // ff3 -> B
        nlspn_prop_meta<false><<<blocksP, threads, 0, stream>>>(
            tapsA, tapsB, affv, auxv, plB, plA, out);                       // ff4 -> A
        nlspn_prop_meta<false><<<blocksP, threads, 0, stream>>>(
            tapsA, tapsB, affv, auxv, plA, plB, out);                       // ff5 -> B
        nlspn_prop_meta<true><<<blocksP, threads, 0, stream>>>(
            tapsA, tapsB, affv, auxv, plB, plA, out);                       // feat6 -> d_out
    } else {
        float* ws = (float*)d_ws;
        nlspn_init_kernel<<<blocksP, threads, 0, stream>>>(pred, conf, out);
        nlspn_prop_kernel<false><<<blocksP, threads, 0, stream>>>(aff_raw, offset, conf, dep, scale, out, ws);
        nlspn_prop_kernel<false><<<blocksP, threads, 0, stream>>>(aff_raw, offset, conf, dep, scale, ws, out);
        nlspn_prop_kernel<false><<<blocksP, threads, 0, stream>>>(aff_raw, offset, conf, dep, scale, out, ws);
        nlspn_prop_kernel<false><<<blocksP, threads, 0, stream>>>(aff_raw, offset, conf, dep, scale, ws, out);
        nlspn_prop_kernel<false><<<blocksP, threads, 0, stream>>>(aff_raw, offset, conf, dep, scale, out, ws);
        nlspn_prop_kernel<true ><<<blocksP, threads, 0, stream>>>(aff_raw, offset, conf, dep, scale, ws, out);
    }
}

// Round 3
// 146.064 us; speedup vs baseline: 1.6813x; 1.0445x over previous
//
#include <hip/hip_runtime.h>
#include <stdint.h>

#define HNUM 240
#define WNUM 1216
#define BNUM 4
#define HWN (HNUM * WNUM)
#define NPIX (BNUM * HWN)
#define NP2 (NPIX / 2)
#define WP (WNUM + 3)
#define HP (HNUM + 3)
#define PLANE (HP * WP)
#define NPLANE (BNUM * PLANE)

union HCV { uint32_t u; _Float16 h[2]; };

// 2-byte-aligned fp16 pair (g00,g01 in one load where HW allows)
struct __attribute__((packed, aligned(2))) H2 { _Float16 lo, hi; };

__device__ __forceinline__ float fast_tanh(float x) {
    float ax = fabsf(x);
    float e  = __builtin_amdgcn_exp2f(ax * 2.885390081777927f);  // 2*log2(e)
    float t  = 1.0f - 2.0f * __builtin_amdgcn_rcpf(e + 1.0f);
    return copysignf(t, x);
}

// one bilinear tap from packed meta on an fp16 plane
__device__ __forceinline__ void tap_f16(uint32_t m, float a,
                                        const _Float16* __restrict__ base,
                                        float& acc) {
    int   rel = (int)(int16_t)(m & 0xffffu);
    float wy  = (float)((m >> 16) & 0xffu) * (1.0f / 255.0f);
    float wx  = (float)(m >> 24)           * (1.0f / 255.0f);
    const _Float16* q = base + rel;
    H2 r0 = *(const H2*)q;
    H2 r1 = *(const H2*)(q + WP);
    float g00 = (float)r0.lo, g01 = (float)r0.hi;
    float g10 = (float)r1.lo, g11 = (float)r1.hi;
    float top = fmaf(wx, g01 - g00, g00);
    float bot = fmaf(wx, g11 - g10, g10);
    acc = fmaf(a, fmaf(wy, bot - top, top), acc);
}

// ---------------------------------------------------------------------------
// init: padded fp16 planes. planeA interior = pred*conf; borders of both = 0.
// ---------------------------------------------------------------------------
__global__ __launch_bounds__(256) void nlspn_init_pad(
    const float* __restrict__ pred,
    const float* __restrict__ conf,
    _Float16* __restrict__ planeA,
    _Float16* __restrict__ planeB)
{
    int i = blockIdx.x * blockDim.x + threadIdx.x;
    if (i >= NPLANE) return;
    int b    = i / PLANE;
    int cell = i - b * PLANE;
    int ph   = cell / WP;
    int pw   = cell - ph * WP;
    int h = ph - 1, w = pw - 1;
    bool interior = (h >= 0) & (h < HNUM) & (w >= 0) & (w < WNUM);
    if (interior) {
        int p = b * HWN + h * WNUM + w;
        planeA[i] = (_Float16)(pred[p] * conf[p]);
    } else {
        planeA[i] = (_Float16)0.f;
        planeB[i] = (_Float16)0.f;
    }
}

// ---------------------------------------------------------------------------
// step 1 fused with meta build (1 px/thread).
// meta per pixel: 8 taps packed u32 (int16 rel | u8 wy | u8 wx),
//                 8 affs fp16, aux = {half2(aref,conf), f32 dep}
// ---------------------------------------------------------------------------
__global__ __launch_bounds__(256) void nlspn_step1_build(
    const float* __restrict__ aff_raw,
    const float* __restrict__ offset,
    const float* __restrict__ conf,
    const float* __restrict__ dep,
    const float* __restrict__ scale,
    const _Float16* __restrict__ ffpad_in,
    _Float16* __restrict__ ffpad_out,
    uint4* __restrict__ tapsA,
    uint4* __restrict__ tapsB,
    uint4* __restrict__ affv,
    uint2* __restrict__ auxv)
{
    int p = blockIdx.x * blockDim.x + threadIdx.x;
    if (p >= NPIX) return;
    int b  = p / HWN;
    int hw = p - b * HWN;
    int h  = hw / WNUM;
    int w  = hw - h * WNUM;

    float s    = scale[0];
    float invs = 1.0f / (s + 1e-8f);

    const float* ar = aff_raw + (size_t)b * 8 * HWN + hw;
    float a[8];
    float asum = 0.f;
#pragma unroll
    for (int k = 0; k < 8; ++k) {
        float t = fast_tanh(ar[(size_t)k * HWN]) * invs;
        a[k] = t;
        asum += fabsf(t);
    }
    asum += 1e-4f;
    float rden = 1.0f / fmaxf(asum, 1.0f);
    float suma = 0.f;
#pragma unroll
    for (int k = 0; k < 8; ++k) { a[k] *= rden; suma += a[k]; }
    float aref = 1.0f - suma;

    const _Float16* base_in = ffpad_in + (size_t)b * PLANE + (h + 1) * WP + (w + 1);
    float acc = aref * (float)base_in[0];

    const float* off = offset + (size_t)b * 16 * HWN + hw;
    uint32_t tw[8];
#pragma unroll
    for (int k = 0; k < 8; ++k) {
        int   k9 = (k < 4) ? k : k + 1;
        int   dy = k9 / 3 - 1;
        int   dx = k9 - (k9 / 3) * 3 - 1;
        float offy = off[(size_t)(2 * k)     * HWN];
        float offx = off[(size_t)(2 * k + 1) * HWN];
        float ys  = (float)(h + dy) + offy;
        float xs  = (float)(w + dx) + offx;
        float y0f = floorf(ys), x0f = floorf(xs);
        int   y0  = (int)y0f,  x0  = (int)x0f;
        float wy  = ys - y0f,  wx  = xs - x0f;
        uint32_t qy = (uint32_t)(wy * 255.0f + 0.5f); if (qy > 255) qy = 255;
        uint32_t qx = (uint32_t)(wx * 255.0f + 0.5f); if (qx > 255) qx = 255;
        bool valid = (y0 >= -1) & (y0 <= HNUM) & (x0 >= -1) & (x0 <= WNUM);
        int rel = (y0 - h) * WP + (x0 - w);
        if (!valid || rel < -32768 || rel > 32767) { rel = 0; qy = 0; qx = 0; a[k] = 0.f; }
        uint32_t m = (uint32_t)(uint16_t)(int16_t)rel | (qy << 16) | (qx << 24);
        tw[k] = m;
        tap_f16(m, a[k], base_in, acc);
    }

    tapsA[p] = make_uint4(tw[0], tw[1], tw[2], tw[3]);
    tapsB[p] = make_uint4(tw[4], tw[5], tw[6], tw[7]);

    HCV cv;
    uint32_t aw[4];
#pragma unroll
    for (int k = 0; k < 4; ++k) {
        cv.h[0] = (_Float16)a[2 * k];
        cv.h[1] = (_Float16)a[2 * k + 1];
        aw[k] = cv.u;
    }
    affv[p] = make_uint4(aw[0], aw[1], aw[2], aw[3]);

    float d = dep[p];
    float c = conf[p];
    cv.h[0] = (_Float16)aref;
    cv.h[1] = (_Float16)c;
    auxv[p] = make_uint2(cv.u, __float_as_uint(d));

    float feat = (d > 0.f) ? d : acc;
    ffpad_out[(size_t)b * PLANE + (h + 1) * WP + (w + 1)] = (_Float16)(feat * c);
}

// ---------------------------------------------------------------------------
// lean propagation step, 2 px/thread, fp16 plane, unconditional gathers
// ---------------------------------------------------------------------------
template <bool LAST>
__global__ __launch_bounds__(256) void nlspn_prop_meta(
    const uint4* __restrict__ tapsA,
    const uint4* __restrict__ tapsB,
    const uint4* __restrict__ affv,
    const uint4* __restrict__ auxv2,   // uint2 aux viewed as uint4 per pixel-pair
    const _Float16* __restrict__ ffin,
    _Float16* __restrict__ ffout,
    float* __restrict__ out)
{
    int t = blockIdx.x * blockDim.x + threadIdx.x;
    if (t >= NP2) return;
    int p0 = 2 * t;
    int p1 = p0 + 1;
    int b   = p0 / HWN;
    int hw0 = p0 - b * HWN;
    int h0  = hw0 / WNUM;
    int w0  = hw0 - h0 * WNUM;
    int h1 = h0, w1 = w0 + 1;
    if (w1 == WNUM) { w1 = 0; ++h1; }

    const _Float16* plane = ffin + (size_t)b * PLANE;
    int bp0 = (h0 + 1) * WP + (w0 + 1);
    int bp1 = (h1 + 1) * WP + (w1 + 1);

    uint4 tA0 = tapsA[p0];
    uint4 tB0 = tapsB[p0];
    uint4 tA1 = tapsA[p1];
    uint4 tB1 = tapsB[p1];
    uint4 av0 = affv[p0];
    uint4 av1 = affv[p1];
    uint4 ax  = auxv2[t];   // {half2(aref0,c0), dep0, half2(aref1,c1), dep1}

    HCV cv;
    float a0[8], a1[8];
    cv.u = av0.x; a0[0] = (float)cv.h[0]; a0[1] = (float)cv.h[1];
    cv.u = av0.y; a0[2] = (float)cv.h[0]; a0[3] = (float)cv.h[1];
    cv.u = av0.z; a0[4] = (float)cv.h[0]; a0[5] = (float)cv.h[1];
    cv.u = av0.w; a0[6] = (float)cv.h[0]; a0[7] = (float)cv.h[1];
    cv.u = av1.x; a1[0] = (float)cv.h[0]; a1[1] = (float)cv.h[1];
    cv.u = av1.y; a1[2] = (float)cv.h[0]; a1[3] = (float)cv.h[1];
    cv.u = av1.z; a1[4] = (float)cv.h[0]; a1[5] = (float)cv.h[1];
    cv.u = av1.w; a1[6] = (float)cv.h[0]; a1[7] = (float)cv.h[1];

    cv.u = ax.x;
    float aref0 = (float)cv.h[0], c0 = (float)cv.h[1];
    float d0 = __uint_as_float(ax.y);
    cv.u = ax.z;
    float aref1 = (float)cv.h[0], c1 = (float)cv.h[1];
    float d1 = __uint_as_float(ax.w);

    const _Float16* base0 = plane + bp0;
    const _Float16* base1 = plane + bp1;
    float acc0 = aref0 * (float)base0[0];
    float acc1 = aref1 * (float)base1[0];

    uint32_t tm0[8] = {tA0.x, tA0.y, tA0.z, tA0.w, tB0.x, tB0.y, tB0.z, tB0.w};
    uint32_t tm1[8] = {tA1.x, tA1.y, tA1.z, tA1.w, tB1.x, tB1.y, tB1.z, tB1.w};
#pragma unroll
    for (int k = 0; k < 8; ++k) {
        tap_f16(tm0[k], a0[k], base0, acc0);
        tap_f16(tm1[k], a1[k], base1, acc1);
    }

    float feat0 = (d0 > 0.f) ? d0 : acc0;
    float feat1 = (d1 > 0.f) ? d1 : acc1;

    if (LAST) {
        *(float2*)(out + p0) = make_float2(feat0, feat1);
    } else {
        _Float16* ob = ffout + (size_t)b * PLANE;
        ob[bp0] = (_Float16)(feat0 * c0);
        ob[bp1] = (_Float16)(feat1 * c1);
    }
}

// ---------------------------------------------------------------------------
// fallback (round-1 style) if workspace is too small
// ---------------------------------------------------------------------------
__global__ __launch_bounds__(256) void nlspn_init_kernel(
    const float* __restrict__ pred,
    const float* __restrict__ conf,
    float* __restrict__ ff)
{
    int p = blockIdx.x * blockDim.x + threadIdx.x;
    if (p < NPIX) ff[p] = pred[p] * conf[p];
}

template <bool LAST>
__global__ __launch_bounds__(256) void nlspn_prop_kernel(
    const float* __restrict__ aff_raw,
    const float* __restrict__ offset,
    const float* __restrict__ conf,
    const float* __restrict__ dep,
    const float* __restrict__ scale,
    const float* __restrict__ ff_in,
    float* __restrict__ out)
{
    int p = blockIdx.x * blockDim.x + threadIdx.x;
    if (p >= NPIX) return;
    int b  = p / HWN;
    int hw = p - b * HWN;
    int h  = hw / WNUM;
    int w  = hw - h * WNUM;

    float s    = scale[0];
    float invs = 1.0f / (s + 1e-8f);

    float a[8];
    const float* ar = aff_raw + (size_t)b * 8 * HWN + hw;
#pragma unroll
    for (int k = 0; k < 8; ++k) a[k] = ar[(size_t)k * HWN];

    float asum = 0.0f;
#pragma unroll
    for (int k = 0; k < 8; ++k) {
        a[k] = fast_tanh(a[k]) * invs;
        asum += fabsf(a[k]);
    }
    asum += 1e-4f;
    float rden = 1.0f / fmaxf(asum, 1.0f);
    float suma = 0.0f;
#pragma unroll
    for (int k = 0; k < 8; ++k) { a[k] *= rden; suma += a[k]; }
    float aref = 1.0f - suma;

    const float* ffb = ff_in + (size_t)b * HWN;
    float acc = aref * ffb[hw];

    const float* off = offset + (size_t)b * 16 * HWN + hw;
#pragma unroll
    for (int k = 0; k < 8; ++k) {
        int   k9 = (k < 4) ? k : k + 1;
        int   dy = k9 / 3 - 1;
        int   dx = k9 - (k9 / 3) * 3 - 1;
        float offy = off[(size_t)(2 * k)     * HWN];
        float offx = off[(size_t)(2 * k + 1) * HWN];
        float ysf = (float)(h + dy) + offy;
        float xsf = (float)(w + dx) + offx;
        float y0f = floorf(ysf);
        float x0f = floorf(xsf);
        float wy  = ysf - y0f;
        float wx  = xsf - x0f;
        int   y0  = (int)y0f;
        int   x0  = (int)x0f;
        bool yv0 = (y0 >= 0)  & (y0 < HNUM);
        bool yv1 = (y0 >= -1) & (y0 + 1 < HNUM);
        bool xv0 = (x0 >= 0)  & (x0 < WNUM);
        bool xv1 = (x0 >= -1) & (x0 + 1 < WNUM);
        int row0 = y0 * WNUM;
        float g00 = 0.f, g01 = 0.f, g10 = 0.f, g11 = 0.f;
        if (yv0 & xv0) g00 = ffb[row0 + x0];
        if (yv0 & xv1) g01 = ffb[row0 + x0 + 1];
        if (yv1 & xv0) g10 = ffb[row0 + WNUM + x0];
        if (yv1 & xv1) g11 = ffb[row0 + WNUM + x0 + 1];
        float sampled = (1.f - wy) * ((1.f - wx) * g00 + wx * g01)
                      +        wy  * ((1.f - wx) * g10 + wx * g11);
        acc += a[k] * sampled;
    }

    float dd   = dep[p];
    float feat = (dd > 0.0f) ? dd : acc;
    if (LAST) out[p] = feat;
    else      out[p] = feat * conf[p];
}

// ---------------------------------------------------------------------------
extern "C" void kernel_launch(void* const* d_in, const int* in_sizes, int n_in,
                              void* d_out, int out_size, void* d_ws, size_t ws_size,
                              hipStream_t stream)
{
    const float* aff_raw = (const float*)d_in[0];
    const float* offset  = (const float*)d_in[1];
    const float* conf    = (const float*)d_in[2];
    const float* pred    = (const float*)d_in[3];
    const float* dep     = (const float*)d_in[4];
    const float* scale   = (const float*)d_in[5];
    float* out = (float*)d_out;

    const int threads = 256;
    const int blocksP = (NPIX + threads - 1) / threads;
    const int blocks2 = (NP2 + threads - 1) / threads;
    const int blocksI = (NPLANE + threads - 1) / threads;

    const size_t need = (size_t)NPIX * 16 * 3 + (size_t)NPIX * 8
                      + (size_t)NPLANE * 2 * 2 + 64;

    if (ws_size >= need) {
        char* wb = (char*)d_ws;
        uint4* tapsA = (uint4*)wb;  wb += (size_t)NPIX * 16;
        uint4* tapsB = (uint4*)wb;  wb += (size_t)NPIX * 16;
        uint4* affv  = (uint4*)wb;  wb += (size_t)NPIX * 16;
        uint2* auxv  = (uint2*)wb;  wb += (size_t)NPIX * 8;
        _Float16* plA = (_Float16*)wb;  wb += (size_t)NPLANE * 2;
        _Float16* plB = (_Float16*)wb;
        const uint4* auxv4 = (const uint4*)auxv;

        nlspn_init_pad<<<blocksI, threads, 0, stream>>>(pred, conf, plA, plB);
        nlspn_step1_build<<<blocksP, threads, 0, stream>>>(
            aff_raw, offset, conf, dep, scale, plA, plB,
            tapsA, tapsB, affv, auxv);                                      // ff1 -> B
        nlspn_prop_meta<false><<<blocks2, threads, 0, stream>>>(
            tapsA, tapsB, affv, auxv4, plB, plA, out);                      // ff2 -> A
        nlspn_prop_meta<false><<<blocks2, threads, 0, stream>>>(
            tapsA, tapsB, affv, auxv4, plA, plB, out);                      // ff3 -> B
        nlspn_prop_meta<false><<<blocks2, threads, 0, stream>>>(
            tapsA, tapsB, affv, auxv4, plB, plA, out);                      // ff4 -> A
        nlspn_prop_meta<false><<<blocks2, threads, 0, stream>>>(
            tapsA, tapsB, affv, auxv4, plA, plB, out);                      // ff5 -> B
        nlspn_prop_meta<true><<<blocks2, threads, 0, stream>>>(
            tapsA, tapsB, affv, auxv4, plB, plA, out);                      // feat6 -> d_out
    } else {
        float* ws = (float*)d_ws;
        nlspn_init_kernel<<<blocksP, threads, 0, stream>>>(pred, conf, out);
        nlspn_prop_kernel<false><<<blocksP, threads, 0, stream>>>(aff_raw, offset, conf, dep, scale, out, ws);
        nlspn_prop_kernel<false><<<blocksP, threads, 0, stream>>>(aff_raw, offset, conf, dep, scale, ws, out);
        nlspn_prop_kernel<false><<<blocksP, threads, 0, stream>>>(aff_raw, offset, conf, dep, scale, out, ws);
        nlspn_prop_kernel<false><<<blocksP, threads, 0, stream>>>(aff_raw, offset, conf, dep, scale, ws, out);
        nlspn_prop_kernel<false><<<blocksP, threads, 0, stream>>>(aff_raw, offset, conf, dep, scale, out, ws);
        nlspn_prop_kernel<true ><<<blocksP, threads, 0, stream>>>(aff_raw, offset, conf, dep, scale, ws, out);
    }
}